// Round 18
// baseline (96.621 us; speedup 1.0000x reference)
//
#include <hip/hip_runtime.h>
#include <hip/hip_bf16.h>

#define NN 8192
#define FIN 512
#define FOUT 256
#define FH 64                 // head-mean output cols
#define JSPLIT 16
#define JCHUNK 512            // per-block j-cols (two 256 halves)

typedef float f32x16 __attribute__((ext_vector_type(16)));
typedef short bf16x8 __attribute__((ext_vector_type(8)));
typedef unsigned short us8 __attribute__((ext_vector_type(8)));
typedef unsigned int uint32x4 __attribute__((ext_vector_type(4)));

static __device__ __forceinline__ unsigned short f2bf(float x) {
  unsigned int u = __builtin_bit_cast(unsigned int, x);
  unsigned int r = (u + 0x7fffu + ((u >> 16) & 1u)) >> 16;  // RNE
  return (unsigned short)r;
}
static __device__ __forceinline__ float bf2f(unsigned short u) {
  unsigned int v = ((unsigned int)u) << 16;
  return __builtin_bit_cast(float, v);
}
static __device__ __forceinline__ float fastexp2(float x) {
  float r;
  asm("v_exp_f32 %0, %1" : "=v"(r) : "v"(x));
  return r;
}
static __device__ __forceinline__ unsigned int pkbf(float a, float b) {
  unsigned int w;
  asm("v_cvt_pk_bf16_f32 %0, %1, %2" : "=v"(w) : "v"(a), "v"(b));
  return w;
}
static __device__ __forceinline__ float lo16f(unsigned int w) {
  return __builtin_bit_cast(float, w << 16);
}
static __device__ __forceinline__ float hi16f(unsigned int w) {
  return __builtin_bit_cast(float, w & 0xffff0000u);
}
// 8-way select of u64 ballots by per-lane index i (0..7)
static __device__ __forceinline__ unsigned long long sel8(int i,
    unsigned long long a0, unsigned long long a1, unsigned long long a2,
    unsigned long long a3, unsigned long long a4, unsigned long long a5,
    unsigned long long a6, unsigned long long a7) {
  unsigned long long s0 = (i & 1) ? a1 : a0;
  unsigned long long s1 = (i & 1) ? a3 : a2;
  unsigned long long s2 = (i & 1) ? a5 : a4;
  unsigned long long s3 = (i & 1) ? a7 : a6;
  unsigned long long t0 = (i & 2) ? s1 : s0;
  unsigned long long t1 = (i & 2) ? s3 : s2;
  return (i & 4) ? t1 : t0;
}

// ---- K1: prep_small — fold head-mean + attention vecs into W fragments ----
// Bw layout: [kt(32)][h(2)][nf(3)][kh(2)][n(32)][e(8)] bf16 (192 KB).
__global__ __launch_bounds__(256) void prep_small(const float* __restrict__ W,
                                                  const float* __restrict__ a,
                                                  unsigned short* __restrict__ Bw) {
  const int kt = blockIdx.x;  // 0..31
  __shared__ float wm[16][64];
  __shared__ float wt[16][2];
  const int t = threadIdx.x;
#pragma unroll
  for (int i = 0; i < 4; ++i) {
    const int idx = t + i * 256;
    const int kr = idx >> 6, c = idx & 63;
    const float* wr = W + (size_t)(kt * 16 + kr) * FOUT + c;
    wm[kr][c] = 0.25f * (wr[0] + wr[64] + wr[128] + wr[192]);
  }
  if (t < 32) {
    const int kr = t & 15, sel = t >> 4;
    const float* wr = W + (size_t)(kt * 16 + kr) * FOUT;
    const float* av = a + sel * FOUT;
    float s = 0.f;
    for (int n = 0; n < FOUT; ++n) s += wr[n] * av[n];
    wt[kr][sel] = s * 1.44269504f;
  }
  __syncthreads();
#pragma unroll
  for (int i = 0; i < 12; ++i) {
    const int idx = t + i * 256;  // within-kt offset < 3072
    const int e = idx & 7, n = (idx >> 3) & 31, r2 = idx >> 8;
    const int khb = r2 & 1, q = r2 >> 1;
    const int nf = q % 3, h = q / 3;
    const int k = khb * 8 + e;
    float v = nf < 2 ? wm[k][nf * 32 + n]
                     : (n == 0 ? wt[k][0] : (n == 1 ? wt[k][1] : 0.f));
    const unsigned short hi = f2bf(v);
    Bw[(size_t)kt * 3072 + idx] = (h == 0) ? hi : f2bf(v - bf2f(hi));
  }
}

// ---- K3: gemm_whm — fused convert_x + Whm = x @ Wm; writes Bg (hi) + s ----
__global__ __launch_bounds__(192) void gemm_whm(const float* __restrict__ X,
                                                const unsigned short* __restrict__ Bw,
                                                unsigned short* __restrict__ Bg,
                                                float* __restrict__ ssrc,
                                                float* __restrict__ sdst) {
  __shared__ float xs[32][516];  // +4 pad
  __shared__ float sred[32][2];
  const int mw = blockIdx.x;
  const int tid = threadIdx.x;
  const float* xb = X + (size_t)(mw * 32) * FIN;
  for (int i = tid; i < 4096; i += 192) {
    const int row = i >> 7, c4 = (i & 127) << 2;
    *(float4*)&xs[row][c4] = *(const float4*)(xb + (size_t)row * FIN + c4);
  }
  __syncthreads();

  const int nf = tid >> 6, lane = tid & 63;
  const int l31 = lane & 31, kh = lane >> 5;
  f32x16 acc = (f32x16)(0.f);
  const unsigned short* bp = Bw + ((size_t)nf * 2 + kh) * 256 + l31 * 8;
#pragma unroll 4
  for (int kt = 0; kt < 32; ++kt) {
    const float* xr = &xs[l31][kt * 16 + kh * 8];
    const float4 va = *(const float4*)xr;
    const float4 vb = *(const float4*)(xr + 4);
    const unsigned int h0 = pkbf(va.x, va.y), h1 = pkbf(va.z, va.w);
    const unsigned int h2 = pkbf(vb.x, vb.y), h3 = pkbf(vb.z, vb.w);
    const unsigned int l0 = pkbf(va.x - lo16f(h0), va.y - hi16f(h0));
    const unsigned int l1 = pkbf(va.z - lo16f(h1), va.w - hi16f(h1));
    const unsigned int l2 = pkbf(vb.x - lo16f(h2), vb.y - hi16f(h2));
    const unsigned int l3 = pkbf(vb.z - lo16f(h3), vb.w - hi16f(h3));
    const uint32x4 uh = {h0, h1, h2, h3}, ul = {l0, l1, l2, l3};
    const bf16x8 a_h = __builtin_bit_cast(bf16x8, uh);
    const bf16x8 a_l = __builtin_bit_cast(bf16x8, ul);
    const bf16x8 b_h = *(const bf16x8*)(bp + kt * 3072);
    const bf16x8 b_l = *(const bf16x8*)(bp + kt * 3072 + 1536);
    acc = __builtin_amdgcn_mfma_f32_32x32x16_bf16(a_h, b_h, acc, 0, 0, 0);
    acc = __builtin_amdgcn_mfma_f32_32x32x16_bf16(a_h, b_l, acc, 0, 0, 0);
    acc = __builtin_amdgcn_mfma_f32_32x32x16_bf16(a_l, b_h, acc, 0, 0, 0);
  }
  if (nf < 2) {
    // Bg per jw(=mw), hi-only: [kc(2)][khb(2)][nf(2)][nn(32)][e(8)] = 2048 sh.
    unsigned short* bgw = Bg + (size_t)mw * 2048;
#pragma unroll
    for (int reg = 0; reg < 16; reg += 2) {
      const unsigned int wh = pkbf(acc[reg], acc[reg + 1]);
      const int e = (reg & 3) | (kh << 2);
      const int khb = (reg >> 2) & 1;
      const int kc = reg >> 3;
      *(unsigned int*)(bgw + (size_t)(((kc * 2 + khb) * 2 + nf) * 256) +
                       l31 * 8 + e) = wh;
    }
  } else if (l31 < 2) {
#pragma unroll
    for (int reg = 0; reg < 16; ++reg) {
      const int row = (reg & 3) + ((reg >> 2) << 3) + (kh << 2);
      sred[row][l31] = acc[reg];
    }
  }
  __syncthreads();
  if (threadIdx.x < 32) {
    ssrc[mw * 32 + threadIdx.x] = sred[threadIdx.x][0];
    sdst[mw * 32 + threadIdx.x] = sred[threadIdx.x][1];
  }
}

// ---- K5: gat_aggr — 4-row x 64-col adj loads (256B bursts), superstep pipe ----
// grid 512 = 32 bm x 16 bj; 1024 thr / 16 waves; wave = 32 rows x 256 j.
// Superstep = 8 insts x (4 rows x 64 cols) = 32 rows x 64 cols = 2 MFMA steps.
// Ballot bit L = (row L>>4, col 4(L&15)+c); lane r picks inst r>>2, shifts
// (r&3)*16 + s*8 -> byte bit k = col 4k+c (identical contract to prior GENAF).
#define GLL(G, L)                                                           \
  __builtin_amdgcn_global_load_lds(                                         \
      (const __attribute__((address_space(1))) unsigned int*)(G),           \
      (__attribute__((address_space(3))) unsigned int*)(L), 16, 0, 0)

// p = exp2( bit ? lr : 0 ); dacc sums raw f32 p.
#define PEL(P, MM, B, SD)                    \
  float P;                                   \
  {                                          \
    float tt = ss + (SD);                    \
    float lr = fmaxf(tt, 0.2f * tt);         \
    lr = (((MM) >> (B)) & 1u) ? lr : 0.0f;   \
    P = fastexp2(lr);                        \
    dacc += P;                               \
  }

#define GENAF(AF, M0, M1, M2, M3, KC4, SA, SB)                            \
  {                                                                       \
    PEL(p0, M0, (KC4) + 0, (SA).x) PEL(p1, M1, (KC4) + 0, (SA).y)         \
    PEL(p2, M2, (KC4) + 0, (SA).z) PEL(p3, M3, (KC4) + 0, (SA).w)         \
    PEL(p4, M0, (KC4) + 1, (SB).x) PEL(p5, M1, (KC4) + 1, (SB).y)         \
    PEL(p6, M2, (KC4) + 1, (SB).z) PEL(p7, M3, (KC4) + 1, (SB).w)         \
    const uint32x4 uv = {pkbf(p0, p1), pkbf(p2, p3), pkbf(p4, p5),        \
                         pkbf(p6, p7)};                                   \
    AF = __builtin_bit_cast(bf16x8, uv);                                  \
  }

__global__ __launch_bounds__(1024, 4) void gat_aggr(
    const int* __restrict__ adj, const float* __restrict__ ssrc_g,
    const float* __restrict__ sdst_g, const unsigned short* __restrict__ Bg,
    unsigned short* __restrict__ Upb, float* __restrict__ Dp) {
  __shared__ unsigned short lbuf[16 * 2048];  // 64 KB: 16 B tiles / acc-xchg
  __shared__ float sds[768];                  // 2 KB sdst + 1 KB dacc-xchg
  const int bid = blockIdx.x;
  const int bj = bid & 15, bm = bid >> 4;
  const int wv = threadIdx.x >> 6, lane = threadIdx.x & 63;
  const int wvr = wv & 7, jhalf = wv >> 3;
  const int l31 = lane & 31, kh = lane >> 5;
  const int rbase = bm * 256;
  const int myrow = rbase + wvr * 32 + l31;
  const int jb = bj * JCHUNK + jhalf * 256;
  const float ss = ssrc_g[myrow];

  // ---- stage B slice (16 tiles, one per wave) + sdst slice ----
  {
    const unsigned short* gs =
        Bg + (size_t)(bj * 16 + wv) * 2048 + lane * 8;
#pragma unroll
    for (int c = 0; c < 4; ++c) GLL(gs + c * 512, &lbuf[wv * 2048 + c * 512]);
    if (wv == 0) {
      GLL(sdst_g + bj * JCHUNK + lane * 4, &sds[0]);
      GLL(sdst_g + bj * JCHUNK + 256 + lane * 4, &sds[256]);
    }
  }

  // ---- adj addressing: inst i -> rows i*4+(lane>>4), cols (lane&15)*4 ----
  const int* astep = adj + (size_t)(rbase + wvr * 32 + (lane >> 4)) * NN + jb +
                     (lane & 15) * 4;
  // ping-pong superstep sets: A = S even, B = S odd (8 int4 each)
  int4 qa0 = *(const int4*)(astep + (size_t)0 * 4 * NN);
  int4 qa1 = *(const int4*)(astep + (size_t)1 * 4 * NN);
  int4 qa2 = *(const int4*)(astep + (size_t)2 * 4 * NN);
  int4 qa3 = *(const int4*)(astep + (size_t)3 * 4 * NN);
  int4 qa4 = *(const int4*)(astep + (size_t)4 * 4 * NN);
  int4 qa5 = *(const int4*)(astep + (size_t)5 * 4 * NN);
  int4 qa6 = *(const int4*)(astep + (size_t)6 * 4 * NN);
  int4 qa7 = *(const int4*)(astep + (size_t)7 * 4 * NN);
  int4 qb0 = *(const int4*)(astep + (size_t)0 * 4 * NN + 64);
  int4 qb1 = *(const int4*)(astep + (size_t)1 * 4 * NN + 64);
  int4 qb2 = *(const int4*)(astep + (size_t)2 * 4 * NN + 64);
  int4 qb3 = *(const int4*)(astep + (size_t)3 * 4 * NN + 64);
  int4 qb4 = *(const int4*)(astep + (size_t)4 * 4 * NN + 64);
  int4 qb5 = *(const int4*)(astep + (size_t)5 * 4 * NN + 64);
  int4 qb6 = *(const int4*)(astep + (size_t)6 * 4 * NN + 64);
  int4 qb7 = *(const int4*)(astep + (size_t)7 * 4 * NN + 64);

  f32x16 acc0 = (f32x16)(0.f), acc1 = (f32x16)(0.f);
  float dacc = 0.f;
  __syncthreads();  // LDS staging landed

  const unsigned short* lb0 = &lbuf[(jhalf * 8) * 2048 + kh * 512 + l31 * 8];
  const float* sdl = &sds[jhalf * 256 + kh * 8];
  const int kh2 = kh * 2;
  const int g16 = (l31 & 3) * 16;
  const int isel = l31 >> 2;

// consume one MFMA step T with per-component byte masks (pre-kh2)
#define CSTEP(T, MK0, MK1, MK2, MK3)                                          \
  {                                                                          \
    const unsigned int m0 = (MK0) >> kh2, m1 = (MK1) >> kh2;                 \
    const unsigned int m2 = (MK2) >> kh2, m3 = (MK3) >> kh2;                 \
    const unsigned short* tb = lb0 + (size_t)(T) * 2048;                     \
    const bf16x8 b00 = *(const bf16x8*)(tb);          /* kc0 nf0 */          \
    const bf16x8 b01 = *(const bf16x8*)(tb + 256);    /* kc0 nf1 */          \
    const bf16x8 b10 = *(const bf16x8*)(tb + 1024);   /* kc1 nf0 */          \
    const bf16x8 b11 = *(const bf16x8*)(tb + 1280);   /* kc1 nf1 */          \
    const float4 sA0 = *(const float4*)(sdl + (T) * 32);                     \
    const float4 sB0 = *(const float4*)(sdl + (T) * 32 + 4);                 \
    const float4 sA1 = *(const float4*)(sdl + (T) * 32 + 16);                \
    const float4 sB1 = *(const float4*)(sdl + (T) * 32 + 20);                \
    bf16x8 af0, af1;                                                         \
    GENAF(af0, m0, m1, m2, m3, 0, sA0, sB0)                                  \
    GENAF(af1, m0, m1, m2, m3, 4, sA1, sB1)                                  \
    acc0 = __builtin_amdgcn_mfma_f32_32x32x16_bf16(af0, b00, acc0, 0, 0, 0); \
    acc1 = __builtin_amdgcn_mfma_f32_32x32x16_bf16(af0, b01, acc1, 0, 0, 0); \
    acc0 = __builtin_amdgcn_mfma_f32_32x32x16_bf16(af1, b10, acc0, 0, 0, 0); \
    acc1 = __builtin_amdgcn_mfma_f32_32x32x16_bf16(af1, b11, acc1, 0, 0, 0); \
  }

#define SSTEP(S, Q0, Q1, Q2, Q3, Q4, Q5, Q6, Q7, RELOAD)                      \
  {                                                                          \
    const unsigned long long sx = sel8(isel,                                 \
        __ballot((Q0).x != 0), __ballot((Q1).x != 0), __ballot((Q2).x != 0), \
        __ballot((Q3).x != 0), __ballot((Q4).x != 0), __ballot((Q5).x != 0), \
        __ballot((Q6).x != 0), __ballot((Q7).x != 0)) >> g16;                \
    const unsigned long long sy = sel8(isel,                                 \
        __ballot((Q0).y != 0), __ballot((Q1).y != 0), __ballot((Q2).y != 0), \
        __ballot((Q3).y != 0), __ballot((Q4).y != 0), __ballot((Q5).y != 0), \
        __ballot((Q6).y != 0), __ballot((Q7).y != 0)) >> g16;                \
    const unsigned long long sz = sel8(isel,                                 \
        __ballot((Q0).z != 0), __ballot((Q1).z != 0), __ballot((Q2).z != 0), \
        __ballot((Q3).z != 0), __ballot((Q4).z != 0), __ballot((Q5).z != 0), \
        __ballot((Q6).z != 0), __ballot((Q7).z != 0)) >> g16;                \
    const unsigned long long sw = sel8(isel,                                 \
        __ballot((Q0).w != 0), __ballot((Q1).w != 0), __ballot((Q2).w != 0), \
        __ballot((Q3).w != 0), __ballot((Q4).w != 0), __ballot((Q5).w != 0), \
        __ballot((Q6).w != 0), __ballot((Q7).w != 0)) >> g16;                \
    if (RELOAD) {                                                            \
      const int* an = astep + ((S) + 2) * 64;                                \
      Q0 = *(const int4*)(an + (size_t)0 * 4 * NN);                          \
      Q1 = *(const int4*)(an + (size_t)1 * 4 * NN);                          \
      Q2 = *(const int4*)(an + (size_t)2 * 4 * NN);                          \
      Q3 = *(const int4*)(an + (size_t)3 * 4 * NN);                          \
      Q4 = *(const int4*)(an + (size_t)4 * 4 * NN);                          \
      Q5 = *(const int4*)(an + (size_t)5 * 4 * NN);                          \
      Q6 = *(const int4*)(an + (size_t)6 * 4 * NN);                          \
      Q7 = *(const int4*)(an + (size_t)7 * 4 * NN);                          \
    }                                                                        \
    CSTEP(2 * (S), (unsigned int)sx, (unsigned int)sy, (unsigned int)sz,     \
          (unsigned int)sw)                                                  \
    CSTEP(2 * (S) + 1, (unsigned int)(sx >> 8), (unsigned int)(sy >> 8),     \
          (unsigned int)(sz >> 8), (unsigned int)(sw >> 8))                  \
  }

  SSTEP(0, qa0, qa1, qa2, qa3, qa4, qa5, qa6, qa7, 1)
  SSTEP(1, qb0, qb1, qb2, qb3, qb4, qb5, qb6, qb7, 1)
  SSTEP(2, qa0, qa1, qa2, qa3, qa4, qa5, qa6, qa7, 0)
  SSTEP(3, qb0, qb1, qb2, qb3, qb4, qb5, qb6, qb7, 0)
#undef SSTEP
#undef CSTEP

  // ---- pairwise reduce waves (w, w+8) through the dead B buffer ----
  dacc += __shfl_xor(dacc, 32);
  __syncthreads();  // all B reads complete; lbuf reusable
  float* lf = (float*)lbuf;
  const int slot = wvr * 2048;
  if (jhalf) {
#pragma unroll
    for (int r = 0; r < 16; ++r) lf[slot + r * 64 + lane] = acc0[r];
#pragma unroll
    for (int r = 0; r < 16; ++r) lf[slot + (16 + r) * 64 + lane] = acc1[r];
    if (lane < 32) sds[512 + wvr * 32 + l31] = dacc;
  }
  __syncthreads();
  if (jhalf) return;
#pragma unroll
  for (int r = 0; r < 16; ++r) acc0[r] += lf[slot + r * 64 + lane];
#pragma unroll
  for (int r = 0; r < 16; ++r) acc1[r] += lf[slot + (16 + r) * 64 + lane];
  dacc += sds[512 + wvr * 32 + l31];

  // ---- D partial ----
  if (lane < 32) Dp[(size_t)bj * NN + myrow] = dacc;

  // ---- U partial: C/D layout col=lane&31, row=(reg&3)+8*(reg>>2)+4*kh ----
  unsigned short* ub = Upb + ((size_t)bj * NN + rbase + wvr * 32) * FH;
#pragma unroll
  for (int reg = 0; reg < 16; ++reg) {
    const int rr = (reg & 3) + ((reg >> 2) << 3) + (kh << 2);
    ub[(size_t)rr * FH + l31] = f2bf(acc0[reg]);
    ub[(size_t)rr * FH + 32 + l31] = f2bf(acc1[reg]);
  }
}

// ---- K6: finalize — combine j-splits, divide (2 outputs/thread) ----
__global__ __launch_bounds__(256) void finalize(const unsigned short* __restrict__ Upb,
                                                const float* __restrict__ Dp,
                                                float* __restrict__ out) {
  const int idx2 = blockIdx.x * 256 + threadIdx.x;  // < 8192*32
  const int i = idx2 >> 5;            // row
  const int c2 = (idx2 & 31) * 2;     // col pair
  const size_t base = (size_t)i * FH + c2;
  float u0 = 0.f, u1 = 0.f, d = 0.f;
#pragma unroll
  for (int s = 0; s < JSPLIT; ++s) {
    d += Dp[(size_t)s * NN + i];
    const unsigned int w =
        *(const unsigned int*)(Upb + (size_t)s * NN * FH + base);
    u0 += bf2f((unsigned short)(w & 0xffffu));
    u1 += bf2f((unsigned short)(w >> 16));
  }
  const float inv = 1.0f / d;
  *(float2*)(out + base) = make_float2(u0 * inv, u1 * inv);
}

extern "C" void kernel_launch(void* const* d_in, const int* in_sizes, int n_in,
                              void* d_out, int out_size, void* d_ws, size_t ws_size,
                              hipStream_t stream) {
  const float* x = (const float*)d_in[0];
  const int* adj = (const int*)d_in[1];
  const float* W = (const float*)d_in[2];
  const float* a = (const float*)d_in[3];
  char* ws = (char*)d_ws;

  // ws layout (~37 MB):
  //   Upb  [0, 16 MB)      bf16 U partials (16 splits)
  //   Bg   [32, 33 MB)     bf16 (hi-only) Whm B-fragments
  //   Bw   36 MB +192 KB; ssrc +256K; sdst +288K; Dp +320K..+832K
  unsigned short* Upb = (unsigned short*)ws;
  unsigned short* Bg = (unsigned short*)(ws + ((size_t)32 << 20));
  unsigned short* Bw = (unsigned short*)(ws + ((size_t)36 << 20));
  float* ssrc = (float*)(ws + ((size_t)36 << 20) + (256u << 10));
  float* sdst = (float*)(ws + ((size_t)36 << 20) + (288u << 10));
  float* Dp = (float*)(ws + ((size_t)36 << 20) + (320u << 10));
  float* out = (float*)d_out;

  prep_small<<<32, 256, 0, stream>>>(W, a, Bw);
  gemm_whm<<<256, 192, 0, stream>>>(x, Bw, Bg, ssrc, sdst);
  gat_aggr<<<32 * JSPLIT, 1024, 0, stream>>>(adj, ssrc, sdst, Bg, Upb, Dp);
  finalize<<<NN * FH / 512, 256, 0, stream>>>(Upb, Dp, out);
}

// Round 19
// 82.696 us; speedup vs baseline: 1.1684x; 1.1684x over previous
//
#include <hip/hip_runtime.h>
#include <hip/hip_bf16.h>

#define NN 8192
#define FIN 512
#define FOUT 256
#define FH 64                 // head-mean output cols
#define JSPLIT 16
#define JCHUNK 512            // per-block j-cols (two 256 halves)
#define STEPS 8               // per-wave steps (256 j / 32)

typedef float f32x16 __attribute__((ext_vector_type(16)));
typedef short bf16x8 __attribute__((ext_vector_type(8)));
typedef unsigned short us8 __attribute__((ext_vector_type(8)));
typedef unsigned int uint32x4 __attribute__((ext_vector_type(4)));

static __device__ __forceinline__ unsigned short f2bf(float x) {
  unsigned int u = __builtin_bit_cast(unsigned int, x);
  unsigned int r = (u + 0x7fffu + ((u >> 16) & 1u)) >> 16;  // RNE
  return (unsigned short)r;
}
static __device__ __forceinline__ float bf2f(unsigned short u) {
  unsigned int v = ((unsigned int)u) << 16;
  return __builtin_bit_cast(float, v);
}
static __device__ __forceinline__ float fastexp2(float x) {
  float r;
  asm("v_exp_f32 %0, %1" : "=v"(r) : "v"(x));
  return r;
}
static __device__ __forceinline__ unsigned int pkbf(float a, float b) {
  unsigned int w;
  asm("v_cvt_pk_bf16_f32 %0, %1, %2" : "=v"(w) : "v"(a), "v"(b));
  return w;
}
static __device__ __forceinline__ float lo16f(unsigned int w) {
  return __builtin_bit_cast(float, w << 16);
}
static __device__ __forceinline__ float hi16f(unsigned int w) {
  return __builtin_bit_cast(float, w & 0xffff0000u);
}
// select 1-of-4 u64 ballots by l31's group bits, extract byte (l31&7)
static __device__ __forceinline__ unsigned int ext4(int l31,
    unsigned long long c0, unsigned long long c1,
    unsigned long long c2, unsigned long long c3) {
  unsigned long long s01 = (l31 & 8) ? c1 : c0;
  unsigned long long s23 = (l31 & 8) ? c3 : c2;
  unsigned long long s = (l31 & 16) ? s23 : s01;
  return (unsigned int)(s >> ((l31 & 7) * 8)) & 0xffu;
}

// ---- K1: prep_small — fold head-mean + attention vecs into W fragments ----
// Bw layout: [kt(32)][h(2)][nf(3)][kh(2)][n(32)][e(8)] bf16 (192 KB).
__global__ __launch_bounds__(256) void prep_small(const float* __restrict__ W,
                                                  const float* __restrict__ a,
                                                  unsigned short* __restrict__ Bw) {
  const int kt = blockIdx.x;  // 0..31
  __shared__ float wm[16][64];
  __shared__ float wt[16][2];
  const int t = threadIdx.x;
#pragma unroll
  for (int i = 0; i < 4; ++i) {
    const int idx = t + i * 256;
    const int kr = idx >> 6, c = idx & 63;
    const float* wr = W + (size_t)(kt * 16 + kr) * FOUT + c;
    wm[kr][c] = 0.25f * (wr[0] + wr[64] + wr[128] + wr[192]);
  }
  if (t < 32) {
    const int kr = t & 15, sel = t >> 4;
    const float* wr = W + (size_t)(kt * 16 + kr) * FOUT;
    const float* av = a + sel * FOUT;
    float s = 0.f;
    for (int n = 0; n < FOUT; ++n) s += wr[n] * av[n];
    wt[kr][sel] = s * 1.44269504f;
  }
  __syncthreads();
#pragma unroll
  for (int i = 0; i < 12; ++i) {
    const int idx = t + i * 256;  // within-kt offset < 3072
    const int e = idx & 7, n = (idx >> 3) & 31, r2 = idx >> 8;
    const int khb = r2 & 1, q = r2 >> 1;
    const int nf = q % 3, h = q / 3;
    const int k = khb * 8 + e;
    float v = nf < 2 ? wm[k][nf * 32 + n]
                     : (n == 0 ? wt[k][0] : (n == 1 ? wt[k][1] : 0.f));
    const unsigned short hi = f2bf(v);
    Bw[(size_t)kt * 3072 + idx] = (h == 0) ? hi : f2bf(v - bf2f(hi));
  }
}

// ---- K3: gemm_whm — fused convert_x + Whm = x @ Wm; writes Bg (hi) + s ----
__global__ __launch_bounds__(192) void gemm_whm(const float* __restrict__ X,
                                                const unsigned short* __restrict__ Bw,
                                                unsigned short* __restrict__ Bg,
                                                float* __restrict__ ssrc,
                                                float* __restrict__ sdst) {
  __shared__ float xs[32][516];  // +4 pad
  __shared__ float sred[32][2];
  const int mw = blockIdx.x;
  const int tid = threadIdx.x;
  const float* xb = X + (size_t)(mw * 32) * FIN;
  for (int i = tid; i < 4096; i += 192) {
    const int row = i >> 7, c4 = (i & 127) << 2;
    *(float4*)&xs[row][c4] = *(const float4*)(xb + (size_t)row * FIN + c4);
  }
  __syncthreads();

  const int nf = tid >> 6, lane = tid & 63;
  const int l31 = lane & 31, kh = lane >> 5;
  f32x16 acc = (f32x16)(0.f);
  const unsigned short* bp = Bw + ((size_t)nf * 2 + kh) * 256 + l31 * 8;
#pragma unroll 4
  for (int kt = 0; kt < 32; ++kt) {
    const float* xr = &xs[l31][kt * 16 + kh * 8];
    const float4 va = *(const float4*)xr;
    const float4 vb = *(const float4*)(xr + 4);
    const unsigned int h0 = pkbf(va.x, va.y), h1 = pkbf(va.z, va.w);
    const unsigned int h2 = pkbf(vb.x, vb.y), h3 = pkbf(vb.z, vb.w);
    const unsigned int l0 = pkbf(va.x - lo16f(h0), va.y - hi16f(h0));
    const unsigned int l1 = pkbf(va.z - lo16f(h1), va.w - hi16f(h1));
    const unsigned int l2 = pkbf(vb.x - lo16f(h2), vb.y - hi16f(h2));
    const unsigned int l3 = pkbf(vb.z - lo16f(h3), vb.w - hi16f(h3));
    const uint32x4 uh = {h0, h1, h2, h3}, ul = {l0, l1, l2, l3};
    const bf16x8 a_h = __builtin_bit_cast(bf16x8, uh);
    const bf16x8 a_l = __builtin_bit_cast(bf16x8, ul);
    const bf16x8 b_h = *(const bf16x8*)(bp + kt * 3072);
    const bf16x8 b_l = *(const bf16x8*)(bp + kt * 3072 + 1536);
    acc = __builtin_amdgcn_mfma_f32_32x32x16_bf16(a_h, b_h, acc, 0, 0, 0);
    acc = __builtin_amdgcn_mfma_f32_32x32x16_bf16(a_h, b_l, acc, 0, 0, 0);
    acc = __builtin_amdgcn_mfma_f32_32x32x16_bf16(a_l, b_h, acc, 0, 0, 0);
  }
  if (nf < 2) {
    // Bg per jw(=mw), hi-only: [kc(2)][khb(2)][nf(2)][nn(32)][e(8)] = 2048 sh.
    unsigned short* bgw = Bg + (size_t)mw * 2048;
#pragma unroll
    for (int reg = 0; reg < 16; reg += 2) {
      const unsigned int wh = pkbf(acc[reg], acc[reg + 1]);
      const int e = (reg & 3) | (kh << 2);
      const int khb = (reg >> 2) & 1;
      const int kc = reg >> 3;
      *(unsigned int*)(bgw + (size_t)(((kc * 2 + khb) * 2 + nf) * 256) +
                       l31 * 8 + e) = wh;
    }
  } else if (l31 < 2) {
#pragma unroll
    for (int reg = 0; reg < 16; ++reg) {
      const int row = (reg & 3) + ((reg >> 2) << 3) + (kh << 2);
      sred[row][l31] = acc[reg];
    }
  }
  __syncthreads();
  if (threadIdx.x < 32) {
    ssrc[mw * 32 + threadIdx.x] = sred[threadIdx.x][0];
    sdst[mw * 32 + threadIdx.x] = sred[threadIdx.x][1];
  }
}

// ---- K5: gat_aggr — 16 waves (2 j-halves), pair-reduced partials ----
// grid 512 = 32 bm x 16 bj; 1024 thr / 16 waves; wave = 32 rows x 256 j.
// Waves w and w+8 share rows, handle j-halves; epilogue pair-reduces via the
// dead B-LDS buffer so only 16 partial sets hit memory.
#define GLL(G, L)                                                           \
  __builtin_amdgcn_global_load_lds(                                         \
      (const __attribute__((address_space(1))) unsigned int*)(G),           \
      (__attribute__((address_space(3))) unsigned int*)(L), 16, 0, 0)

// p = exp2( bit ? lr : 0 ); dacc sums raw f32 p.
#define PEL(P, MM, B, SD)                    \
  float P;                                   \
  {                                          \
    float tt = ss + (SD);                    \
    float lr = fmaxf(tt, 0.2f * tt);         \
    lr = (((MM) >> (B)) & 1u) ? lr : 0.0f;   \
    P = fastexp2(lr);                        \
    dacc += P;                               \
  }

#define GENAF(AF, M0, M1, M2, M3, KC4, SA, SB)                            \
  {                                                                       \
    PEL(p0, M0, (KC4) + 0, (SA).x) PEL(p1, M1, (KC4) + 0, (SA).y)         \
    PEL(p2, M2, (KC4) + 0, (SA).z) PEL(p3, M3, (KC4) + 0, (SA).w)         \
    PEL(p4, M0, (KC4) + 1, (SB).x) PEL(p5, M1, (KC4) + 1, (SB).y)         \
    PEL(p6, M2, (KC4) + 1, (SB).z) PEL(p7, M3, (KC4) + 1, (SB).w)         \
    const uint32x4 uv = {pkbf(p0, p1), pkbf(p2, p3), pkbf(p4, p5),        \
                         pkbf(p6, p7)};                                   \
    AF = __builtin_bit_cast(bf16x8, uv);                                  \
  }

__global__ __launch_bounds__(1024, 4) void gat_aggr(
    const int* __restrict__ adj, const float* __restrict__ ssrc_g,
    const float* __restrict__ sdst_g, const unsigned short* __restrict__ Bg,
    unsigned short* __restrict__ Upb, float* __restrict__ Dp) {
  __shared__ unsigned short lbuf[16 * 2048];  // 64 KB: 16 B tiles / acc-xchg
  __shared__ float sds[768];                  // 2 KB sdst + 1 KB dacc-xchg
  const int bid = blockIdx.x;
  const int bj = bid & 15, bm = bid >> 4;
  const int wv = threadIdx.x >> 6, lane = threadIdx.x & 63;
  const int wvr = wv & 7, jhalf = wv >> 3;
  const int l31 = lane & 31, kh = lane >> 5;
  const int rbase = bm * 256;
  const int myrow = rbase + wvr * 32 + l31;
  const int jb = bj * JCHUNK + jhalf * 256;
  const float ss = ssrc_g[myrow];

  // ---- stage B slice (16 tiles, one per wave) + sdst slice ----
  {
    const unsigned short* gs =
        Bg + (size_t)(bj * 16 + wv) * 2048 + lane * 8;
#pragma unroll
    for (int c = 0; c < 4; ++c) GLL(gs + c * 512, &lbuf[wv * 2048 + c * 512]);
    if (wv == 0) {
      GLL(sdst_g + bj * JCHUNK + lane * 4, &sds[0]);
      GLL(sdst_g + bj * JCHUNK + 256 + lane * 4, &sds[256]);
    }
  }

  // ---- per-lane adj addressing: inst i -> row i*8+(lane>>3), quad lane&7 ----
  const int* astep = adj + (size_t)(rbase + wvr * 32 + (lane >> 3)) * NN + jb +
                     (lane & 7) * 4;
  // ping-pong sets: A = even steps, B = odd steps
  int4 qa0 = *(const int4*)(astep + (size_t)0 * 8 * NN);
  int4 qa1 = *(const int4*)(astep + (size_t)1 * 8 * NN);
  int4 qa2 = *(const int4*)(astep + (size_t)2 * 8 * NN);
  int4 qa3 = *(const int4*)(astep + (size_t)3 * 8 * NN);
  int4 qb0 = *(const int4*)(astep + (size_t)0 * 8 * NN + 32);
  int4 qb1 = *(const int4*)(astep + (size_t)1 * 8 * NN + 32);
  int4 qb2 = *(const int4*)(astep + (size_t)2 * 8 * NN + 32);
  int4 qb3 = *(const int4*)(astep + (size_t)3 * 8 * NN + 32);

  f32x16 acc0 = (f32x16)(0.f), acc1 = (f32x16)(0.f);
  float dacc = 0.f;
  __syncthreads();  // LDS staging landed

  const unsigned short* lb0 = &lbuf[(jhalf * 8) * 2048 + kh * 512 + l31 * 8];
  const float* sdl = &sds[jhalf * 256 + kh * 8];
  const int kh2 = kh * 2;

#define PSTEP(T, QS0, QS1, QS2, QS3, RELOAD)                                  \
  {                                                                          \
    const unsigned int mk0 = ext4(l31, __ballot((QS0).x != 0),               \
        __ballot((QS1).x != 0), __ballot((QS2).x != 0), __ballot((QS3).x != 0)); \
    const unsigned int mk1 = ext4(l31, __ballot((QS0).y != 0),               \
        __ballot((QS1).y != 0), __ballot((QS2).y != 0), __ballot((QS3).y != 0)); \
    const unsigned int mk2 = ext4(l31, __ballot((QS0).z != 0),               \
        __ballot((QS1).z != 0), __ballot((QS2).z != 0), __ballot((QS3).z != 0)); \
    const unsigned int mk3 = ext4(l31, __ballot((QS0).w != 0),               \
        __ballot((QS1).w != 0), __ballot((QS2).w != 0), __ballot((QS3).w != 0)); \
    if (RELOAD) {                                                            \
      const int* an = astep + ((T) + 2) * 32;                                \
      QS0 = *(const int4*)(an + (size_t)0 * 8 * NN);                         \
      QS1 = *(const int4*)(an + (size_t)1 * 8 * NN);                         \
      QS2 = *(const int4*)(an + (size_t)2 * 8 * NN);                         \
      QS3 = *(const int4*)(an + (size_t)3 * 8 * NN);                         \
    }                                                                        \
    const unsigned int m0 = mk0 >> kh2, m1 = mk1 >> kh2;                     \
    const unsigned int m2 = mk2 >> kh2, m3 = mk3 >> kh2;                     \
    const unsigned short* tb = lb0 + (size_t)(T) * 2048;                     \
    const bf16x8 b00 = *(const bf16x8*)(tb);          /* kc0 nf0 */          \
    const bf16x8 b01 = *(const bf16x8*)(tb + 256);    /* kc0 nf1 */          \
    const bf16x8 b10 = *(const bf16x8*)(tb + 1024);   /* kc1 nf0 */          \
    const bf16x8 b11 = *(const bf16x8*)(tb + 1280);   /* kc1 nf1 */          \
    const float4 sA0 = *(const float4*)(sdl + (T) * 32);                     \
    const float4 sB0 = *(const float4*)(sdl + (T) * 32 + 4);                 \
    const float4 sA1 = *(const float4*)(sdl + (T) * 32 + 16);                \
    const float4 sB1 = *(const float4*)(sdl + (T) * 32 + 20);                \
    bf16x8 af0, af1;                                                         \
    GENAF(af0, m0, m1, m2, m3, 0, sA0, sB0)                                  \
    GENAF(af1, m0, m1, m2, m3, 4, sA1, sB1)                                  \
    acc0 = __builtin_amdgcn_mfma_f32_32x32x16_bf16(af0, b00, acc0, 0, 0, 0); \
    acc1 = __builtin_amdgcn_mfma_f32_32x32x16_bf16(af0, b01, acc1, 0, 0, 0); \
    acc0 = __builtin_amdgcn_mfma_f32_32x32x16_bf16(af1, b10, acc0, 0, 0, 0); \
    acc1 = __builtin_amdgcn_mfma_f32_32x32x16_bf16(af1, b11, acc1, 0, 0, 0); \
  }

#pragma unroll 1
  for (int it = 0; it < 3; ++it) {
    const int t0 = 2 * it;
    PSTEP(t0, qa0, qa1, qa2, qa3, 1)
    PSTEP(t0 + 1, qb0, qb1, qb2, qb3, 1)
  }
  PSTEP(6, qa0, qa1, qa2, qa3, 0)
  PSTEP(7, qb0, qb1, qb2, qb3, 0)
#undef PSTEP

  // ---- pairwise reduce waves (w, w+8) through the dead B buffer ----
  dacc += __shfl_xor(dacc, 32);
  __syncthreads();  // all B reads complete; lbuf reusable
  float* lf = (float*)lbuf;
  const int slot = wvr * 2048;
  if (jhalf) {
#pragma unroll
    for (int r = 0; r < 16; ++r) lf[slot + r * 64 + lane] = acc0[r];
#pragma unroll
    for (int r = 0; r < 16; ++r) lf[slot + (16 + r) * 64 + lane] = acc1[r];
    if (lane < 32) sds[512 + wvr * 32 + l31] = dacc;
  }
  __syncthreads();
  if (jhalf) return;
#pragma unroll
  for (int r = 0; r < 16; ++r) acc0[r] += lf[slot + r * 64 + lane];
#pragma unroll
  for (int r = 0; r < 16; ++r) acc1[r] += lf[slot + (16 + r) * 64 + lane];
  dacc += sds[512 + wvr * 32 + l31];

  // ---- D partial ----
  if (lane < 32) Dp[(size_t)bj * NN + myrow] = dacc;

  // ---- U partial: C/D layout col=lane&31, row=(reg&3)+8*(reg>>2)+4*kh ----
  unsigned short* ub = Upb + ((size_t)bj * NN + rbase + wvr * 32) * FH;
#pragma unroll
  for (int reg = 0; reg < 16; ++reg) {
    const int rr = (reg & 3) + ((reg >> 2) << 3) + (kh << 2);
    ub[(size_t)rr * FH + l31] = f2bf(acc0[reg]);
    ub[(size_t)rr * FH + 32 + l31] = f2bf(acc1[reg]);
  }
}

// ---- K6: finalize — combine j-splits, divide (2 outputs/thread) ----
__global__ __launch_bounds__(256) void finalize(const unsigned short* __restrict__ Upb,
                                                const float* __restrict__ Dp,
                                                float* __restrict__ out) {
  const int idx2 = blockIdx.x * 256 + threadIdx.x;  // < 8192*32
  const int i = idx2 >> 5;            // row
  const int c2 = (idx2 & 31) * 2;     // col pair
  const size_t base = (size_t)i * FH + c2;
  float u0 = 0.f, u1 = 0.f, d = 0.f;
#pragma unroll
  for (int s = 0; s < JSPLIT; ++s) {
    d += Dp[(size_t)s * NN + i];
    const unsigned int w =
        *(const unsigned int*)(Upb + (size_t)s * NN * FH + base);
    u0 += bf2f((unsigned short)(w & 0xffffu));
    u1 += bf2f((unsigned short)(w >> 16));
  }
  const float inv = 1.0f / d;
  *(float2*)(out + base) = make_float2(u0 * inv, u1 * inv);
}

extern "C" void kernel_launch(void* const* d_in, const int* in_sizes, int n_in,
                              void* d_out, int out_size, void* d_ws, size_t ws_size,
                              hipStream_t stream) {
  const float* x = (const float*)d_in[0];
  const int* adj = (const int*)d_in[1];
  const float* W = (const float*)d_in[2];
  const float* a = (const float*)d_in[3];
  char* ws = (char*)d_ws;

  // ws layout (~37 MB):
  //   Upb  [0, 16 MB)      bf16 U partials (16 splits)
  //   Bg   [32, 33 MB)     bf16 (hi-only) Whm B-fragments
  //   Bw   36 MB +192 KB; ssrc +256K; sdst +288K; Dp +320K..+832K
  unsigned short* Upb = (unsigned short*)ws;
  unsigned short* Bg = (unsigned short*)(ws + ((size_t)32 << 20));
  unsigned short* Bw = (unsigned short*)(ws + ((size_t)36 << 20));
  float* ssrc = (float*)(ws + ((size_t)36 << 20) + (256u << 10));
  float* sdst = (float*)(ws + ((size_t)36 << 20) + (288u << 10));
  float* Dp = (float*)(ws + ((size_t)36 << 20) + (320u << 10));
  float* out = (float*)d_out;

  prep_small<<<32, 256, 0, stream>>>(W, a, Bw);
  gemm_whm<<<256, 192, 0, stream>>>(x, Bw, Bg, ssrc, sdst);
  gat_aggr<<<32 * JSPLIT, 1024, 0, stream>>>(adj, ssrc, sdst, Bg, Upb, Dp);
  finalize<<<NN * FH / 512, 256, 0, stream>>>(Upb, Dp, out);
}